// Round 3
// baseline (3868.490 us; speedup 1.0000x reference)
//
#include <hip/hip_runtime.h>
#include <hip/hip_fp16.h>

#define Tn 1024
#define NB 128

// sigmoid(x) = 1/(1+exp2(S_RZ*x)); tanh(y): e=exp2(S_N*y), n=(1-e)/(1+e)
#define S_RZ (-1.4426950408889634f)
#define S_N  (-2.8853900817779268f)

typedef _Float16 f16x8 __attribute__((ext_vector_type(8)));
typedef _Float16 f16x4 __attribute__((ext_vector_type(4)));
typedef float    f32x4 __attribute__((ext_vector_type(4)));

// ---- Phase 1: token table gv2[d][v][64 quads][16]:
// slots 0-3: S_RZ*(gi_r+bhh_r), 4-7: S_RZ*(gi_z+bhh_z), 8-11: S_N*gi_n, 12-15: S_N*bhh_n
__global__ __launch_bounds__(768)
void gv_build(const float* __restrict__ emb,
              const float* __restrict__ wihf, const float* __restrict__ bihf, const float* __restrict__ bhhf,
              const float* __restrict__ wihb, const float* __restrict__ bihb, const float* __restrict__ bhhb,
              _Float16* __restrict__ gv2)
{
  const int d  = blockIdx.x >> 7;
  const int v4 = (blockIdx.x & 127) * 4;
  const float* wih = d ? wihb : wihf;
  const float* bih = d ? bihb : bihf;
  const float* bhh = d ? bhhb : bhhf;
  __shared__ float se[4][128];
  const int tid = threadIdx.x;
  if (tid < 512) se[tid >> 7][tid & 127] = emb[(v4 + (tid >> 7)) * 128 + (tid & 127)];
  __syncthreads();
  const int row = tid, g = row >> 8, j = row & 255;
  const float b0 = bih[row];
  float a0 = b0, a1 = b0, a2 = b0, a3 = b0;
  #pragma unroll
  for (int e = 0; e < 128; e += 4) {
    const float4 w = *reinterpret_cast<const float4*>(&wih[row * 128 + e]);
    a0 = fmaf(w.x, se[0][e], a0); a0 = fmaf(w.y, se[0][e+1], a0);
    a0 = fmaf(w.z, se[0][e+2], a0); a0 = fmaf(w.w, se[0][e+3], a0);
    a1 = fmaf(w.x, se[1][e], a1); a1 = fmaf(w.y, se[1][e+1], a1);
    a1 = fmaf(w.z, se[1][e+2], a1); a1 = fmaf(w.w, se[1][e+3], a1);
    a2 = fmaf(w.x, se[2][e], a2); a2 = fmaf(w.y, se[2][e+1], a2);
    a2 = fmaf(w.z, se[2][e+2], a2); a2 = fmaf(w.w, se[2][e+3], a2);
    a3 = fmaf(w.x, se[3][e], a3); a3 = fmaf(w.y, se[3][e+1], a3);
    a3 = fmaf(w.z, se[3][e+2], a3); a3 = fmaf(w.w, se[3][e+3], a3);
  }
  const float sc  = (g == 2) ? S_N : S_RZ;
  const float add = (g < 2) ? bhh[row] : 0.f;
  _Float16* base = gv2 + ((size_t)(d * 512 + v4) * 64 + (j >> 2)) * 16 + g * 4 + (j & 3);
  base[0]    = (_Float16)(sc * (a0 + add));
  base[1024] = (_Float16)(sc * (a1 + add));
  base[2048] = (_Float16)(sc * (a2 + add));
  base[3072] = (_Float16)(sc * (a3 + add));
  if (g == 2) {
    const _Float16 bv = (_Float16)(S_N * bhh[row]);   // row = 512+j
    _Float16* bb = gv2 + ((size_t)(d * 512 + v4) * 64 + (j >> 2)) * 16 + 12 + (j & 3);
    bb[0] = bv; bb[1024] = bv; bb[2048] = bv; bb[3072] = bv;
  }
}

// ---- Phase 2: batched GRU scan via MFMA.
// 16 wg = (2 dir) x (8 groups of 16 batches). 512 threads = 8 waves, 2 waves/SIMD.
// Per step: D[768 gates x 16 batch] = Whh_f16(regs, scaled) x h_f16(LDS). Wave w owns
// gate j-blocks {w, w+8} (r,z,n tiles colocated). Wave 7 adds the emission tile (fcw).
__global__ __launch_bounds__(512, 2)
void gru_scan(const int* __restrict__ x,
              const _Float16* __restrict__ gv2,
              const float* __restrict__ whhf,
              const float* __restrict__ whhb,
              const float* __restrict__ fcw,
              float* __restrict__ em)
{
  const int tid = threadIdx.x;
  const int w   = tid >> 6;       // wave 0..7
  const int l   = tid & 63;
  const int m   = l & 15;         // batch-in-group / MFMA row-or-col lane index
  const int q   = l >> 4;         // k-quarter
  const int dir = blockIdx.x & 1;
  const int b0  = (blockIdx.x >> 1) * 16;

  const float* whh = dir ? whhb : whhf;

  __shared__ _Float16 hls[2][16][264];   // double-buffered h, 264-pad rows
  __shared__ _Float16 emf[8][512];       // emission A-frags per k-step

  // h init (both buffers)
  for (int i = tid; i < 2 * 16 * 264; i += 512) (&hls[0][0][0])[i] = (_Float16)0.f;

  // Emission A-frag table (wave 7): slot(q,e) = fcw[label][dir*256 + ks*32 + q*8 + e]
  if (w == 7) {
    #pragma unroll
    for (int ks = 0; ks < 8; ++ks) {
      f16x8 f;
      #pragma unroll
      for (int e = 0; e < 8; ++e) {
        float v = (m < 4) ? fcw[m * 512 + dir * 256 + ks * 32 + q * 8 + e] : 0.f;
        f[e] = (_Float16)v;
      }
      *reinterpret_cast<f16x8*>(&emf[ks][l * 8]) = f;
    }
  }

  // Weight A-frags: af[blk][g][ks], slot(q,e) = sc * whh[g*256 + (w+8blk)*16 + m][ks*32+q*8+e]
  f16x8 af[2][3][8];
  #pragma unroll
  for (int blk = 0; blk < 2; ++blk) {
    #pragma unroll
    for (int g = 0; g < 3; ++g) {
      const int row = g * 256 + (w + 8 * blk) * 16 + m;
      const float sc = (g == 2) ? S_N : S_RZ;
      const float* wrow = whh + (size_t)row * 256 + q * 8;
      #pragma unroll
      for (int ks = 0; ks < 8; ++ks) {
        const float4 c0 = *reinterpret_cast<const float4*>(wrow + ks * 32);
        const float4 c1 = *reinterpret_cast<const float4*>(wrow + ks * 32 + 4);
        f16x8 f;
        f[0] = (_Float16)(c0.x * sc); f[1] = (_Float16)(c0.y * sc);
        f[2] = (_Float16)(c0.z * sc); f[3] = (_Float16)(c0.w * sc);
        f[4] = (_Float16)(c1.x * sc); f[5] = (_Float16)(c1.y * sc);
        f[6] = (_Float16)(c1.z * sc); f[7] = (_Float16)(c1.w * sc);
        af[blk][g][ks] = f;
      }
    }
  }
  __syncthreads();

  const int*      xrow = x + (size_t)(b0 + m) * Tn;
  const _Float16* gvd  = gv2 + (size_t)dir * 512 * 1024;
  float*          emo  = em + (size_t)(dir * NB + b0 + m) * (Tn * 4);

  int tok = xrow[dir ? (Tn - 1) : 0];

  for (int t = 0; t < Tn; ++t) {
    const int cur = t & 1;
    const _Float16* hc = &hls[cur][0][0];
    _Float16*       hn = &hls[cur ^ 1][0][0];

    // token-table loads (this step) + next-token prefetch
    const _Float16* gp0 = gvd + (size_t)tok * 1024 + ((w + 0) * 4 + q) * 16;
    const _Float16* gp1 = gvd + (size_t)tok * 1024 + ((w + 8) * 4 + q) * 16;
    const f16x8 rz0 = *reinterpret_cast<const f16x8*>(gp0);
    const f16x8 nb0 = *reinterpret_cast<const f16x8*>(gp0 + 8);
    const f16x8 rz1 = *reinterpret_cast<const f16x8*>(gp1);
    const f16x8 nb1 = *reinterpret_cast<const f16x8*>(gp1 + 8);
    if (t + 1 < Tn) tok = xrow[dir ? (Tn - 2 - t) : (t + 1)];

    // h_old for this lane's output slots
    const f16x4 ho0 = *reinterpret_cast<const f16x4*>(hc + m * 264 + (w + 0) * 16 + q * 4);
    const f16x4 ho1 = *reinterpret_cast<const f16x4*>(hc + m * 264 + (w + 8) * 16 + q * 4);

    // GEMM phase
    f32x4 acc[2][3] = {{{0,0,0,0},{0,0,0,0},{0,0,0,0}},{{0,0,0,0},{0,0,0,0},{0,0,0,0}}};
    f32x4 acce = {0,0,0,0};
    #pragma unroll
    for (int ks = 0; ks < 8; ++ks) {
      const f16x8 b = *reinterpret_cast<const f16x8*>(hc + m * 264 + ks * 32 + q * 8);
      #pragma unroll
      for (int blk = 0; blk < 2; ++blk) {
        acc[blk][0] = __builtin_amdgcn_mfma_f32_16x16x32_f16(af[blk][0][ks], b, acc[blk][0], 0, 0, 0);
        acc[blk][1] = __builtin_amdgcn_mfma_f32_16x16x32_f16(af[blk][1][ks], b, acc[blk][1], 0, 0, 0);
        acc[blk][2] = __builtin_amdgcn_mfma_f32_16x16x32_f16(af[blk][2][ks], b, acc[blk][2], 0, 0, 0);
      }
      if (w == 7) {
        const f16x8 ef = *reinterpret_cast<const f16x8*>(&emf[ks][l * 8]);
        acce = __builtin_amdgcn_mfma_f32_16x16x32_f16(ef, b, acce, 0, 0, 0);
      }
    }

    // emission store (h_{t-1}): wave 7, lanes 0-15 hold labels 0-3 in acce[0..3]
    if (w == 7 && t > 0 && l < 16) {
      const int ptt = dir ? (Tn - t) : (t - 1);
      *reinterpret_cast<f32x4*>(emo + (size_t)ptt * 4) = acce;
    }

    // h-update: 8 elements per lane (2 blocks x 4 regs)
    #pragma unroll
    for (int blk = 0; blk < 2; ++blk) {
      const f16x8 rzv = blk ? rz1 : rz0;
      const f16x8 nbv = blk ? nb1 : nb0;
      const f16x4 hov = blk ? ho1 : ho0;
      f16x4 hnv;
      #pragma unroll
      for (int r4 = 0; r4 < 4; ++r4) {
        const float aR = acc[blk][0][r4], aZ = acc[blk][1][r4], aN = acc[blk][2][r4];
        const float pr = aR + (float)rzv[r4];
        const float er = __builtin_amdgcn_exp2f(pr);
        const float rr = __builtin_amdgcn_rcpf(1.f + er);
        const float pz = aZ + (float)rzv[4 + r4];
        const float ez = __builtin_amdgcn_exp2f(pz);
        const float zz = __builtin_amdgcn_rcpf(1.f + ez);
        float y = fmaf(rr, aN + (float)nbv[4 + r4], (float)nbv[r4]);
        y = fminf(y, 60.f);  // exp2 overflow guard (avoid inf*0=NaN)
        const float en = __builtin_amdgcn_exp2f(y);
        const float nn = (1.f - en) * __builtin_amdgcn_rcpf(1.f + en);
        const float hv = fmaf(zz, (float)hov[r4] - nn, nn);
        hnv[r4] = (_Float16)hv;
      }
      *reinterpret_cast<f16x4*>(hn + m * 264 + (w + 8 * blk) * 16 + q * 4) = hnv;
    }
    __syncthreads();
  }

  // final emission (h_{T-1} in buffer Tn&1 = 0)
  if (w == 7) {
    const _Float16* hc = &hls[Tn & 1][0][0];
    f32x4 acce = {0,0,0,0};
    #pragma unroll
    for (int ks = 0; ks < 8; ++ks) {
      const f16x8 b  = *reinterpret_cast<const f16x8*>(hc + m * 264 + ks * 32 + q * 8);
      const f16x8 ef = *reinterpret_cast<const f16x8*>(&emf[ks][l * 8]);
      acce = __builtin_amdgcn_mfma_f32_16x16x32_f16(ef, b, acce, 0, 0, 0);
    }
    if (l < 16) {
      const int ptt = dir ? 0 : (Tn - 1);
      *reinterpret_cast<f32x4*>(emo + (size_t)ptt * 4) = acce;
    }
  }
}

// ---- Phase 3: CRF negative log-likelihood per batch (4 lanes per batch element)
__global__ __launch_bounds__(64)
void crf_nllh(const int* __restrict__ tags,
              const float* __restrict__ em,
              const float* __restrict__ fc_b,
              const float* __restrict__ st,
              const float* __restrict__ et,
              const float* __restrict__ tr,
              float* __restrict__ llh)
{
  const int lane = threadIdx.x;
  const int l = lane & 3;
  const int q = lane >> 2;
  const int b = blockIdx.x * 16 + q;
  const float* ef = em + (size_t)b * Tn * 4;
  const float* eb = em + ((size_t)NB + b) * Tn * 4;
  const int* tg = tags + b * Tn;
  const float fcb = fc_b[l];
  const float tc0 = tr[l * 4 + l];
  const float tc1 = tr[(l ^ 1) * 4 + l];
  const float tc2 = tr[(l ^ 2) * 4 + l];
  const float tc3 = tr[(l ^ 3) * 4 + l];

  const float e0 = ef[l] + eb[l] + fcb;
  float alpha = st[l] + e0;
  int tprev = tg[0];
  float score = (tprev == l) ? (st[l] + e0) : 0.f;

  #pragma unroll 8
  for (int t = 1; t < Tn; ++t) {
    const float e = ef[t * 4 + l] + eb[t * 4 + l] + fcb;
    const int tc = tg[t];
    if (tc == l) {
      const int s2 = tprev ^ l;
      const float tsel = (s2 & 1) ? ((s2 & 2) ? tc3 : tc1)
                                  : ((s2 & 2) ? tc2 : tc0);
      score += e + tsel;
    }
    tprev = tc;
    const float a1 = __shfl_xor(alpha, 1);
    const float a2 = __shfl_xor(alpha, 2);
    const float a3 = __shfl_xor(alpha, 3);
    const float v0 = alpha + tc0;
    const float v1 = a1 + tc1;
    const float v2 = a2 + tc2;
    const float v3 = a3 + tc3;
    const float mx = fmaxf(fmaxf(v0, v1), fmaxf(v2, v3));
    const float s = __expf(v0 - mx) + __expf(v1 - mx) + __expf(v2 - mx) + __expf(v3 - mx);
    alpha = mx + __logf(s) + e;
  }

  score += (tprev == l) ? et[l] : 0.f;
  float ae = alpha + et[l];
  float m1 = fmaxf(ae, __shfl_xor(ae, 1));
  m1 = fmaxf(m1, __shfl_xor(m1, 2));
  float se = __expf(ae - m1);
  se += __shfl_xor(se, 1);
  se += __shfl_xor(se, 2);
  const float logZ = m1 + __logf(se);
  float sc = score + __shfl_xor(score, 1);
  sc += __shfl_xor(sc, 2);
  if (l == 0) llh[b] = sc - logZ;
}

// ---- Phase 4: out = -mean(llh)
__global__ __launch_bounds__(128)
void reduce_mean(const float* __restrict__ llh, float* __restrict__ out)
{
  const int t = threadIdx.x;
  float v = llh[t];
  #pragma unroll
  for (int m = 32; m >= 1; m >>= 1) v += __shfl_xor(v, m);
  __shared__ float s2[2];
  if ((t & 63) == 0) s2[t >> 6] = v;
  __syncthreads();
  if (t == 0) out[0] = -(s2[0] + s2[1]) * (1.f / 128.f);
}

extern "C" void kernel_launch(void* const* d_in, const int* in_sizes, int n_in,
                              void* d_out, int out_size, void* d_ws, size_t ws_size,
                              hipStream_t stream) {
  const int*   x    = (const int*)d_in[0];
  const int*   tags = (const int*)d_in[1];
  // d_in[2] = mask (all ones) -- unused
  const float* emb  = (const float*)d_in[3];
  const float* wihf = (const float*)d_in[4];
  const float* whhf = (const float*)d_in[5];
  const float* bihf = (const float*)d_in[6];
  const float* bhhf = (const float*)d_in[7];
  const float* wihb = (const float*)d_in[8];
  const float* whhb = (const float*)d_in[9];
  const float* bihb = (const float*)d_in[10];
  const float* bhhb = (const float*)d_in[11];
  const float* fcw  = (const float*)d_in[12];
  const float* fcb  = (const float*)d_in[13];
  const float* st   = (const float*)d_in[14];
  const float* et   = (const float*)d_in[15];
  const float* tr   = (const float*)d_in[16];

  char* ws = (char*)d_ws;
  _Float16* gv2 = (_Float16*)ws;                    // 2*512*64*16*2 = 2,097,152 B
  float*    em  = (float*)(ws + 2097152);           // 2*128*1024*4*4 = 4,194,304 B
  float*    llh = (float*)(ws + 2097152 + 4194304); // 512 B

  gv_build<<<dim3(256), dim3(768), 0, stream>>>(emb, wihf, bihf, bhhf, wihb, bihb, bhhb, gv2);
  gru_scan<<<dim3(16), dim3(512), 0, stream>>>(x, gv2, whhf, whhb, fcw, em);
  crf_nllh<<<dim3(8), dim3(64), 0, stream>>>(tags, em, fcb, st, et, tr, llh);
  reduce_mean<<<dim3(1), dim3(128), 0, stream>>>(llh, (float*)d_out);
}

// Round 4
// 1655.021 us; speedup vs baseline: 2.3374x; 2.3374x over previous
//
#include <hip/hip_runtime.h>
#include <hip/hip_fp16.h>

#define Tn 1024
#define NB 128

typedef _Float16 h2_t __attribute__((ext_vector_type(2)));

__device__ __forceinline__ float dot2f(h2_t a, h2_t b, float c) {
#if __has_builtin(__builtin_amdgcn_fdot2)
  return __builtin_amdgcn_fdot2(a, b, c, false);
#else
  return c + (float)a[0] * (float)b[0] + (float)a[1] * (float)b[1];
#endif
}

__device__ __forceinline__ h2_t u2h(unsigned u) {
  union { unsigned u; h2_t h; } c; c.u = u; return c.h;
}

// quad_perm DPP xor-adds (VALU pipe)
__device__ __forceinline__ float dpp_xor1(float v) {
  int i = __builtin_bit_cast(int, v);
  return __builtin_bit_cast(float, __builtin_amdgcn_update_dpp(i, i, 0xB1, 0xF, 0xF, true));
}
__device__ __forceinline__ float dpp_xor2(float v) {
  int i = __builtin_bit_cast(int, v);
  return __builtin_bit_cast(float, __builtin_amdgcn_update_dpp(i, i, 0x4E, 0xF, 0xF, true));
}

// ---- Phase 1: gv[d][v][row] = emb[v] . w_ih_d[row] + b_ih_d[row]  (row in [0,768))
__global__ __launch_bounds__(768)
void gv_build(const float* __restrict__ emb,
              const float* __restrict__ wihf, const float* __restrict__ bihf,
              const float* __restrict__ wihb, const float* __restrict__ bihb,
              float* __restrict__ gv)
{
  const int d  = blockIdx.x >> 7;
  const int v4 = (blockIdx.x & 127) * 4;
  const float* wih = d ? wihb : wihf;
  const float* bih = d ? bihb : bihf;
  __shared__ float se[4][128];
  const int tid = threadIdx.x;
  if (tid < 512) se[tid >> 7][tid & 127] = emb[(v4 + (tid >> 7)) * 128 + (tid & 127)];
  __syncthreads();
  const int row = tid;
  const float b0 = bih[row];
  float a0 = b0, a1 = b0, a2 = b0, a3 = b0;
  #pragma unroll
  for (int e = 0; e < 128; e += 4) {
    const float4 w = *reinterpret_cast<const float4*>(&wih[row * 128 + e]);
    a0 = fmaf(w.x, se[0][e], a0); a0 = fmaf(w.y, se[0][e+1], a0);
    a0 = fmaf(w.z, se[0][e+2], a0); a0 = fmaf(w.w, se[0][e+3], a0);
    a1 = fmaf(w.x, se[1][e], a1); a1 = fmaf(w.y, se[1][e+1], a1);
    a1 = fmaf(w.z, se[1][e+2], a1); a1 = fmaf(w.w, se[1][e+3], a1);
    a2 = fmaf(w.x, se[2][e], a2); a2 = fmaf(w.y, se[2][e+1], a2);
    a2 = fmaf(w.z, se[2][e+2], a2); a2 = fmaf(w.w, se[2][e+3], a2);
    a3 = fmaf(w.x, se[3][e], a3); a3 = fmaf(w.y, se[3][e+1], a3);
    a3 = fmaf(w.z, se[3][e+2], a3); a3 = fmaf(w.w, se[3][e+3], a3);
  }
  float* out = gv + (size_t)(d * 512 + v4) * 768 + row;
  out[0] = a0; out[768] = a1; out[1536] = a2; out[2304] = a3;
}

// ---- Phase 2: per-(batch,dir) GRU scan.
// 768 threads = 12 waves (3/SIMD, 170-VGPR cap). Thread (rid=tid>>2, q=tid&3) owns
// gate rows 4rid..4rid+3 restricted to k in [64q,64q+64): 128 h2 weight regs.
// Quad partial sums combined via DPP; r/z/n recombined through dls[] LDS exchange.
// h stored f16 with 16B-per-quarter stagger (q*144B) -> conflict-free b128 reads.
// Waves 0-3: h-update; waves 4-7: lagged emission dot; waves 8-11 idle in phase 2.
__global__ __launch_bounds__(768, 3)
void gru_scan(const int* __restrict__ x,
              const float* __restrict__ gv,
              const float* __restrict__ whhf,
              const float* __restrict__ whhb,
              const float* __restrict__ bhhf,
              const float* __restrict__ bhhb,
              const float* __restrict__ fcw,
              float* __restrict__ em)
{
  const int tid = threadIdx.x;
  const int rid = tid >> 2;   // row-group (rows 4rid..4rid+3)
  const int q   = tid & 3;    // k-quarter
  const int dir = blockIdx.x & 1;
  const int b   = blockIdx.x >> 1;

  const float* whh = dir ? whhb : whhf;
  const float* bhh = dir ? bhhb : bhhf;

  __shared__ __align__(16) char hls[2][576];     // h f16, 4 quarters @ 144B stride
  __shared__ float dls[768];                     // gate-dot exchange
  __shared__ __align__(8) _Float16 fcs[4][256];  // fc weights (dir slice)

  // Weights straight from global (one-time; L2-shared across wgs).
  h2_t w[128];
  #pragma unroll
  for (int i = 0; i < 4; ++i) {
    const float* wrow = whh + (size_t)(4 * rid + i) * 256 + q * 64;
    #pragma unroll
    for (int c = 0; c < 16; ++c) {
      const float4 f = reinterpret_cast<const float4*>(wrow)[c];
      h2_t a; a[0] = (_Float16)f.x; a[1] = (_Float16)f.y;
      h2_t bb; bb[0] = (_Float16)f.z; bb[1] = (_Float16)f.w;
      w[i * 32 + 2 * c] = a;
      w[i * 32 + 2 * c + 1] = bb;
    }
  }
  float4 bias = make_float4(0.f, 0.f, 0.f, 0.f);
  if (q == 0) bias = *reinterpret_cast<const float4*>(bhh + 4 * rid);

  for (int i = tid; i < 1024; i += 768)
    fcs[i >> 8][i & 255] = (_Float16)fcw[(i >> 8) * 512 + dir * 256 + (i & 255)];
  if (tid < 144) reinterpret_cast<uint2*>(hls)[tid] = make_uint2(0, 0);
  __syncthreads();

  const float* gvd = gv + (size_t)dir * (512 * 768);
  const int*   xb  = x + b * Tn;
  float*       emo = em + (size_t)(dir * NB + b) * (Tn * 4);

  const bool updt = tid < 256;
  float ho = 0.f;
  int tok = updt ? xb[dir ? (Tn - 1) : 0] : 0;

  for (int t = 0; t < Tn; ++t) {
    const int cur = t & 1;

    // prefetch token-table values + next token (hidden under the dot phase)
    float gir = 0.f, giz = 0.f, gin = 0.f;
    int ntok = 0;
    if (updt) {
      const float* g = gvd + (size_t)tok * 768 + tid;
      gir = g[0]; giz = g[256]; gin = g[512];
      ntok = xb[(t + 1 < Tn) ? (dir ? (Tn - 2 - t) : (t + 1)) : 0];
    }

    // dots: 4 rows x 64 k per thread
    const char* hbase = hls[cur] + q * 144;
    float a0 = bias.x, a1 = bias.y, a2 = bias.z, a3 = bias.w;
    #pragma unroll
    for (int c = 0; c < 8; ++c) {
      const uint4 hq = *reinterpret_cast<const uint4*>(hbase + c * 16);
      const h2_t h0 = u2h(hq.x), h1 = u2h(hq.y), h2v = u2h(hq.z), h3 = u2h(hq.w);
      a0 = dot2f(w[     4*c+0], h0, a0); a0 = dot2f(w[     4*c+1], h1, a0);
      a0 = dot2f(w[     4*c+2], h2v, a0); a0 = dot2f(w[     4*c+3], h3, a0);
      a1 = dot2f(w[32 + 4*c+0], h0, a1); a1 = dot2f(w[32 + 4*c+1], h1, a1);
      a1 = dot2f(w[32 + 4*c+2], h2v, a1); a1 = dot2f(w[32 + 4*c+3], h3, a1);
      a2 = dot2f(w[64 + 4*c+0], h0, a2); a2 = dot2f(w[64 + 4*c+1], h1, a2);
      a2 = dot2f(w[64 + 4*c+2], h2v, a2); a2 = dot2f(w[64 + 4*c+3], h3, a2);
      a3 = dot2f(w[96 + 4*c+0], h0, a3); a3 = dot2f(w[96 + 4*c+1], h1, a3);
      a3 = dot2f(w[96 + 4*c+2], h2v, a3); a3 = dot2f(w[96 + 4*c+3], h3, a3);
    }
    // quad combine (lanes 4rid..4rid+3), then lane q keeps row 4rid+q
    a0 += dpp_xor1(a0); a0 += dpp_xor2(a0);
    a1 += dpp_xor1(a1); a1 += dpp_xor2(a1);
    a2 += dpp_xor1(a2); a2 += dpp_xor2(a2);
    a3 += dpp_xor1(a3); a3 += dpp_xor2(a3);
    const float v01 = (q & 1) ? a1 : a0;
    const float v23 = (q & 1) ? a3 : a2;
    dls[tid] = (q & 2) ? v23 : v01;   // dls[row] = full dot of row (row == tid)
    __syncthreads();

    if (updt) {
      const float dr = dls[tid], dz = dls[tid + 256], dn = dls[tid + 512];
      const float r    = 1.f / (1.f + __expf(-(gir + dr)));
      const float z    = 1.f / (1.f + __expf(-(giz + dz)));
      const float npre = gin + r * dn;
      const float e2   = __expf(-2.f * npre);
      const float n    = (1.f - e2) / (1.f + e2);
      const float hnew = (1.f - z) * n + z * ho;
      ho = hnew;
      tok = ntok;
      *reinterpret_cast<_Float16*>(hls[cur ^ 1] + (tid >> 6) * 144 + (tid & 63) * 2) =
          (_Float16)hnew;
    } else if (tid < 512 && t > 0) {
      // emission of h_{t-1} (= hls[cur]); wave per label, lane p owns 4 k-elems
      const int e = tid - 256, l = e >> 6, p = e & 63;
      const uint2 hq = *reinterpret_cast<const uint2*>(hls[cur] + (p >> 4) * 144 + (p & 15) * 8);
      const h2_t* fr = reinterpret_cast<const h2_t*>(&fcs[l][0]);
      float a = dot2f(fr[2 * p], u2h(hq.x), 0.f);
      a = dot2f(fr[2 * p + 1], u2h(hq.y), a);
      a += __shfl_xor(a, 1);  a += __shfl_xor(a, 2);  a += __shfl_xor(a, 4);
      a += __shfl_xor(a, 8);  a += __shfl_xor(a, 16); a += __shfl_xor(a, 32);
      if (p == 0) {
        const int ptt = dir ? (Tn - t) : (t - 1);
        emo[ptt * 4 + l] = a;
      }
    }
    __syncthreads();
  }

  // final emission: h_{T-1} lives in hls[Tn&1]
  if (tid >= 256 && tid < 512) {
    const int e = tid - 256, l = e >> 6, p = e & 63;
    const uint2 hq = *reinterpret_cast<const uint2*>(hls[Tn & 1] + (p >> 4) * 144 + (p & 15) * 8);
    const h2_t* fr = reinterpret_cast<const h2_t*>(&fcs[l][0]);
    float a = dot2f(fr[2 * p], u2h(hq.x), 0.f);
    a = dot2f(fr[2 * p + 1], u2h(hq.y), a);
    a += __shfl_xor(a, 1);  a += __shfl_xor(a, 2);  a += __shfl_xor(a, 4);
    a += __shfl_xor(a, 8);  a += __shfl_xor(a, 16); a += __shfl_xor(a, 32);
    if (p == 0) {
      const int ptt = dir ? 0 : (Tn - 1);
      emo[ptt * 4 + l] = a;
    }
  }
}

// ---- Phase 3: CRF negative log-likelihood per batch (4 lanes per batch element)
__global__ __launch_bounds__(64)
void crf_nllh(const int* __restrict__ tags,
              const float* __restrict__ em,
              const float* __restrict__ fc_b,
              const float* __restrict__ st,
              const float* __restrict__ et,
              const float* __restrict__ tr,
              float* __restrict__ llh)
{
  const int lane = threadIdx.x;
  const int l = lane & 3;
  const int q = lane >> 2;
  const int b = blockIdx.x * 16 + q;
  const float* ef = em + (size_t)b * Tn * 4;
  const float* eb = em + ((size_t)NB + b) * Tn * 4;
  const int* tg = tags + b * Tn;
  const float fcb = fc_b[l];
  const float tc0 = tr[l * 4 + l];
  const float tc1 = tr[(l ^ 1) * 4 + l];
  const float tc2 = tr[(l ^ 2) * 4 + l];
  const float tc3 = tr[(l ^ 3) * 4 + l];

  const float e0 = ef[l] + eb[l] + fcb;
  float alpha = st[l] + e0;
  int tprev = tg[0];
  float score = (tprev == l) ? (st[l] + e0) : 0.f;

  #pragma unroll 8
  for (int t = 1; t < Tn; ++t) {
    const float e = ef[t * 4 + l] + eb[t * 4 + l] + fcb;
    const int tc = tg[t];
    if (tc == l) {
      const int s2 = tprev ^ l;
      const float tsel = (s2 & 1) ? ((s2 & 2) ? tc3 : tc1)
                                  : ((s2 & 2) ? tc2 : tc0);
      score += e + tsel;
    }
    tprev = tc;
    const float a1 = __shfl_xor(alpha, 1);
    const float a2 = __shfl_xor(alpha, 2);
    const float a3 = __shfl_xor(alpha, 3);
    const float v0 = alpha + tc0;
    const float v1 = a1 + tc1;
    const float v2 = a2 + tc2;
    const float v3 = a3 + tc3;
    const float mx = fmaxf(fmaxf(v0, v1), fmaxf(v2, v3));
    const float s = __expf(v0 - mx) + __expf(v1 - mx) + __expf(v2 - mx) + __expf(v3 - mx);
    alpha = mx + __logf(s) + e;
  }

  score += (tprev == l) ? et[l] : 0.f;
  float ae = alpha + et[l];
  float m1 = fmaxf(ae, __shfl_xor(ae, 1));
  m1 = fmaxf(m1, __shfl_xor(m1, 2));
  float se = __expf(ae - m1);
  se += __shfl_xor(se, 1);
  se += __shfl_xor(se, 2);
  const float logZ = m1 + __logf(se);
  float sc = score + __shfl_xor(score, 1);
  sc += __shfl_xor(sc, 2);
  if (l == 0) llh[b] = sc - logZ;
}

// ---- Phase 4: out = -mean(llh)
__global__ __launch_bounds__(128)
void reduce_mean(const float* __restrict__ llh, float* __restrict__ out)
{
  const int t = threadIdx.x;
  float v = llh[t];
  #pragma unroll
  for (int m = 32; m >= 1; m >>= 1) v += __shfl_xor(v, m);
  __shared__ float s2[2];
  if ((t & 63) == 0) s2[t >> 6] = v;
  __syncthreads();
  if (t == 0) out[0] = -(s2[0] + s2[1]) * (1.f / 128.f);
}

extern "C" void kernel_launch(void* const* d_in, const int* in_sizes, int n_in,
                              void* d_out, int out_size, void* d_ws, size_t ws_size,
                              hipStream_t stream) {
  const int*   x    = (const int*)d_in[0];
  const int*   tags = (const int*)d_in[1];
  // d_in[2] = mask (all ones) -- unused
  const float* emb  = (const float*)d_in[3];
  const float* wihf = (const float*)d_in[4];
  const float* whhf = (const float*)d_in[5];
  const float* bihf = (const float*)d_in[6];
  const float* bhhf = (const float*)d_in[7];
  const float* wihb = (const float*)d_in[8];
  const float* whhb = (const float*)d_in[9];
  const float* bihb = (const float*)d_in[10];
  const float* bhhb = (const float*)d_in[11];
  const float* fcw  = (const float*)d_in[12];
  const float* fcb  = (const float*)d_in[13];
  const float* st   = (const float*)d_in[14];
  const float* et   = (const float*)d_in[15];
  const float* tr   = (const float*)d_in[16];

  char* ws = (char*)d_ws;
  float* gv  = (float*)ws;                          // 2*512*768*4   = 3,145,728 B
  float* em  = (float*)(ws + 3145728);              // 2*128*1024*4*4 = 4,194,304 B
  float* llh = (float*)(ws + 3145728 + 4194304);    // 512 B

  gv_build<<<dim3(256), dim3(768), 0, stream>>>(emb, wihf, bihf, wihb, bihb, gv);
  gru_scan<<<dim3(256), dim3(768), 0, stream>>>(x, gv, whhf, whhb, bhhf, bhhb, fcw, em);
  crf_nllh<<<dim3(8), dim3(64), 0, stream>>>(tags, em, fcb, st, et, tr, llh);
  reduce_mean<<<dim3(1), dim3(128), 0, stream>>>(llh, (float*)d_out);
}